// Round 7
// baseline (283.856 us; speedup 1.0000x reference)
//
#include <hip/hip_runtime.h>
#include <math.h>

#define BB 4
#define LL 1024
#define DD 512
#define HH 8
#define DEP 64
#define NEGV (-1.0e9f)

typedef __attribute__((ext_vector_type(8))) short bf16x8;
typedef __attribute__((ext_vector_type(4))) float f32x4;
typedef unsigned short u16;
typedef unsigned int u32;

// ---- scalar slots in ws (float offsets) ----
#define S_TMAX 1
#define S_TMIN 2
#define S_MUL  4     // 4
#define S_SUM  8     // 32
#define S_M    40    // 32
#define P_TMAX 128   // 256 partials (table scan)
#define P_TMIN 384   // 256 partials
#define P_GMAX 640   // 1024 partials (k3: 16 qstripes x 32 bh x 2 kz)
#define SCAL_F 1792
#define PER_T  (BB*HH*LL*DEP)   // 2097152 bf16 elems per tensor

__device__ inline u16 f2b(float x) {
  u32 u = __float_as_uint(x);
  return (u16)((u + 0x7FFFu + ((u >> 16) & 1u)) >> 16);
}
__device__ inline float b2f(u16 h) { return __uint_as_float(((u32)h) << 16); }

__device__ inline void atomicMaxF(float* addr, float val) {
  unsigned int* ua = (unsigned int*)addr;
  unsigned int old = *ua;
  while (__uint_as_float(old) < val) {
    unsigned int assumed = old;
    old = atomicCAS(ua, assumed, __float_as_uint(val));
    if (old == assumed) break;
  }
}

// ---- k_prep: [0,2048) xb | [2048,2304) wt | [2304,2560) table scan
//              [2560,2564) protok count | 2564 init ----
__global__ __launch_bounds__(256) void k_prep(
    const float* __restrict__ q, const float* __restrict__ kv,
    const float* __restrict__ wq, const float* __restrict__ wk,
    const float* __restrict__ wv, const float* __restrict__ wo,
    const float* __restrict__ hb, const float* __restrict__ pi,
    const float* __restrict__ protok,
    u16* __restrict__ Xb, u16* __restrict__ WTb, float* __restrict__ ws) {
  const int bid = blockIdx.x;
  const int t = threadIdx.x;
  if (bid < 2048) {                    // ---- xb: f32 -> bf16 convert of q|kv
    int tg = bid*256 + t;
    int which = tg >> 18;
    size_t off8 = (size_t)(tg & 262143) * 8;
    const float* s = which ? kv : q;
    float4 f0 = *(const float4*)&s[off8];
    float4 f1 = *(const float4*)&s[off8 + 4];
    u32 p0 = (u32)f2b(f0.x) | ((u32)f2b(f0.y) << 16);
    u32 p1 = (u32)f2b(f0.z) | ((u32)f2b(f0.w) << 16);
    u32 p2 = (u32)f2b(f1.x) | ((u32)f2b(f1.y) << 16);
    u32 p3 = (u32)f2b(f1.z) | ((u32)f2b(f1.w) << 16);
    *(int4*)&Xb[(size_t)which*PER_T + off8] = make_int4(p0, p1, p2, p3);
  } else if (bid < 2304) {             // ---- weight transpose -> WT[g][n][k]
    const int wid = bid - 2048;
    const int g = wid >> 6, rem = wid & 63;
    const int k0 = (rem >> 3)*64, n0 = (rem & 7)*64;
    const float* W = (g==0)?wq:(g==1)?wk:(g==2)?wv:wo;
    __shared__ u16 Ls[64][72];
    {
      const int r = t>>2, c16 = (t&3)*16;
      float v[16];
      #pragma unroll
      for (int j=0;j<4;++j) {
        float4 f = *(const float4*)&W[(size_t)(k0+r)*DD + n0 + c16 + 4*j];
        v[4*j]=f.x; v[4*j+1]=f.y; v[4*j+2]=f.z; v[4*j+3]=f.w;
      }
      u32 pk_[8];
      #pragma unroll
      for (int j=0;j<8;++j) pk_[j] = (u32)f2b(v[2*j]) | ((u32)f2b(v[2*j+1])<<16);
      *(int4*)&Ls[r][c16]   = make_int4(pk_[0],pk_[1],pk_[2],pk_[3]);
      *(int4*)&Ls[r][c16+8] = make_int4(pk_[4],pk_[5],pk_[6],pk_[7]);
    }
    __syncthreads();
    {
      const int n = t>>2, kk = (t&3)*16;
      u16 u[16];
      #pragma unroll
      for (int j=0;j<16;++j) u[j] = Ls[kk+j][n];
      u32 q_[8];
      #pragma unroll
      for (int j=0;j<8;++j) q_[j] = (u32)u[2*j] | ((u32)u[2*j+1]<<16);
      size_t dst = ((size_t)(g*DD + n0 + n))*DD + k0 + kk;
      *(int4*)&WTb[dst]   = make_int4(q_[0],q_[1],q_[2],q_[3]);
      *(int4*)&WTb[dst+8] = make_int4(q_[4],q_[5],q_[6],q_[7]);
    }
  } else if (bid < 2560) {             // ---- table min/max partials
    const int g = (bid - 2304)*256 + t;
    float mx = -INFINITY, mn = INFINITY;
    #pragma unroll
    for (int rep = 0; rep < 4; ++rep) {
      float4 a[4], c[4];
      #pragma unroll
      for (int j = 0; j < 4; ++j) {
        size_t idx = (size_t)rep*262144 + (size_t)j*65536 + g;
        a[j] = ((const float4*)hb)[idx];
        c[j] = ((const float4*)pi)[idx];
      }
      #pragma unroll
      for (int j = 0; j < 4; ++j) {
        mx = fmaxf(mx, fmaxf(fmaxf(a[j].x, a[j].y), fmaxf(a[j].z, a[j].w)));
        mx = fmaxf(mx, fmaxf(fmaxf(c[j].x, c[j].y), fmaxf(c[j].z, c[j].w)));
        mn = fminf(mn, fminf(fminf(a[j].x, a[j].y), fminf(a[j].z, a[j].w)));
        mn = fminf(mn, fminf(fminf(c[j].x, c[j].y), fminf(c[j].z, c[j].w)));
      }
    }
    __shared__ float shx[4], shn[4];
    int lane = t & 63, w = t >> 6;
    #pragma unroll
    for (int o = 32; o > 0; o >>= 1) {
      mx = fmaxf(mx, __shfl_down(mx, o));
      mn = fminf(mn, __shfl_down(mn, o));
    }
    if (lane == 0) { shx[w] = mx; shn[w] = mn; }
    __syncthreads();
    if (t == 0) {
      ws[P_TMAX + bid - 2304] = fmaxf(fmaxf(shx[0], shx[1]), fmaxf(shx[2], shx[3]));
      ws[P_TMIN + bid - 2304] = fminf(fminf(shn[0], shn[1]), fminf(shn[2], shn[3]));
    }
  } else if (bid < 2564) {             // ---- protok count
    int b = bid - 2560;
    int cnt = 0;
    for (int l = t; l < LL; l += 256)
      cnt += (protok[b*LL + l] != 0.0f) ? 1 : 0;
    __shared__ int shc[4];
    int lane = t & 63, w = t >> 6;
    #pragma unroll
    for (int o = 32; o > 0; o >>= 1) cnt += __shfl_down(cnt, o);
    if (lane == 0) shc[w] = cnt;
    __syncthreads();
    if (t == 0) ws[S_MUL + b] = (float)(shc[0] + shc[1] + shc[2] + shc[3]);
  } else {                             // ---- init S_SUM / S_M
    if (t < 32) { ws[S_SUM + t] = 0.0f; ws[S_M + t] = -INFINITY; }
  }
}

// ---- K1: three projections via MFMA, direct-fragment loads (no LDS for A/B) ----
__global__ __launch_bounds__(256) void k1_proj(
    const float* __restrict__ protok,
    const float* __restrict__ bq, const float* __restrict__ bk,
    const float* __restrict__ bv,
    const u16* __restrict__ Xb, const u16* __restrict__ WTb,
    u16* __restrict__ QPb, u16* __restrict__ KHb, u16* __restrict__ VTb) {
  const int gid = blockIdx.z;
  const u16* X = Xb + (gid == 0 ? 0 : (size_t)PER_T);
  const float* bia = (gid == 0) ? bq : (gid == 1) ? bk : bv;
  const int m0 = blockIdx.x*64;
  const int h  = blockIdx.y;
  __shared__ u16 As[64][72];   // used only for gid==2 V-transpose bounce
  const int t = threadIdx.x;
  const int w = t>>6, lane = t&63, i = lane&15, g2 = lane>>4;

  const u16* Xr = X + (size_t)(m0 + 16*w + i)*DD;
  const u16* Wb = WTb + ((size_t)gid*DD + h*64)*DD;

  f32x4 acc[4];
  #pragma unroll
  for (int ct=0;ct<4;++ct) acc[ct] = (f32x4){0.f,0.f,0.f,0.f};

  #pragma unroll
  for (int kk0 = 0; kk0 < DD; kk0 += 64) {
    bf16x8 a0 = *(const bf16x8*)&Xr[kk0 + g2*8];
    bf16x8 a1 = *(const bf16x8*)&Xr[kk0 + 32 + g2*8];
    #pragma unroll
    for (int ct=0; ct<4; ++ct) {
      bf16x8 b0 = *(const bf16x8*)&Wb[(size_t)(ct*16+i)*DD + kk0 + g2*8];
      bf16x8 b1 = *(const bf16x8*)&Wb[(size_t)(ct*16+i)*DD + kk0 + 32 + g2*8];
      acc[ct] = __builtin_amdgcn_mfma_f32_16x16x32_bf16(a0, b0, acc[ct], 0,0,0);
      acc[ct] = __builtin_amdgcn_mfma_f32_16x16x32_bf16(a1, b1, acc[ct], 0,0,0);
    }
  }
  const int lrow = 16*w + g2*4;
  if (gid == 2) {
    #pragma unroll
    for (int ct=0;ct<4;++ct)
      #pragma unroll
      for (int r=0;r<4;++r)
        As[lrow + r][ct*16 + i] = f2b(acc[ct][r] + bia[h*64 + ct*16 + i]);
    __syncthreads();
    const int b = m0 >> 10, l0 = m0 & 1023;
    const int d = t>>2, lc = (t&3)*16;
    u16 u[16];
    #pragma unroll
    for (int j=0;j<16;++j) u[j] = As[lc+j][d];
    u32 q_[8];
    #pragma unroll
    for (int j=0;j<8;++j) q_[j] = (u32)u[2*j] | ((u32)u[2*j+1]<<16);
    size_t dst = ((size_t)(b*HH + h)*DEP + d)*LL + l0 + lc;
    *(int4*)&VTb[dst]   = make_int4(q_[0],q_[1],q_[2],q_[3]);
    *(int4*)&VTb[dst+8] = make_int4(q_[4],q_[5],q_[6],q_[7]);
  } else {
    u16* Y = (gid == 0) ? QPb : KHb;
    #pragma unroll
    for (int ct=0;ct<4;++ct)
      #pragma unroll
      for (int r=0;r<4;++r) {
        int m = m0 + lrow + r;
        float keep = (gid == 0) ? ((protok[m] != 0.0f) ? 1.0f : 0.0f) : 1.0f;
        int b = m >> 10, l = m & 1023;
        float val = (acc[ct][r] + bia[h*64 + ct*16 + i]) * keep;
        Y[((size_t)(b*HH + h)*LL + l)*DEP + ct*16 + i] = f2b(val);
      }
  }
}

// ---- K3: partial max of raw QK^T; zero-LDS, barrier-free, direct frags ----
__global__ __launch_bounds__(256) void k3_gmax(
    const u16* __restrict__ QPb, const u16* __restrict__ KHb,
    float* __restrict__ wsf) {
  const int q0 = blockIdx.x*64, bh = blockIdx.y, kz = blockIdx.z;  // (16,32,2)
  const int t = threadIdx.x;
  const int w = t>>6, lane = t&63, i = lane&15, g2 = lane>>4;
  const u16* Qr = QPb + ((size_t)bh*LL + q0 + 16*w + i)*DEP;
  bf16x8 aq0 = *(const bf16x8*)&Qr[g2*8];
  bf16x8 aq1 = *(const bf16x8*)&Qr[32 + g2*8];
  const u16* Kb = KHb + (size_t)bh*LL*DEP;
  const int kbase = kz*512;
  float mx = -INFINITY;
  bf16x8 c0[4], c1[4];
  #pragma unroll
  for (int ct=0;ct<4;++ct) {
    c0[ct] = *(const bf16x8*)&Kb[(size_t)(kbase + ct*16+i)*DEP + g2*8];
    c1[ct] = *(const bf16x8*)&Kb[(size_t)(kbase + ct*16+i)*DEP + 32 + g2*8];
  }
  #pragma unroll
  for (int kt = 0; kt < 8; ++kt) {
    bf16x8 n0[4], n1[4];
    if (kt < 7) {
      #pragma unroll
      for (int ct=0;ct<4;++ct) {
        n0[ct] = *(const bf16x8*)&Kb[(size_t)(kbase + (kt+1)*64 + ct*16+i)*DEP + g2*8];
        n1[ct] = *(const bf16x8*)&Kb[(size_t)(kbase + (kt+1)*64 + ct*16+i)*DEP + 32 + g2*8];
      }
    }
    #pragma unroll
    for (int ct=0;ct<4;++ct) {
      f32x4 z = (f32x4){0.f,0.f,0.f,0.f};
      z = __builtin_amdgcn_mfma_f32_16x16x32_bf16(aq0, c0[ct], z, 0,0,0);
      z = __builtin_amdgcn_mfma_f32_16x16x32_bf16(aq1, c1[ct], z, 0,0,0);
      mx = fmaxf(mx, fmaxf(fmaxf(z[0],z[1]), fmaxf(z[2],z[3])));
    }
    if (kt < 7) {
      #pragma unroll
      for (int ct=0;ct<4;++ct) { c0[ct] = n0[ct]; c1[ct] = n1[ct]; }
    }
  }
  __shared__ float red[4];
  #pragma unroll
  for (int o = 32; o > 0; o >>= 1) mx = fmaxf(mx, __shfl_down(mx, o));
  if (lane == 0) red[w] = mx;
  __syncthreads();
  if (t == 0)
    wsf[P_GMAX + (bh*16 + blockIdx.x)*2 + kz] =
        fmaxf(fmaxf(red[0],red[1]), fmaxf(red[2],red[3]));
}

// ---- K4: fused QK^T -> normalize+table+mask -> exp -> sum/max -> P^T V ----
__global__ __launch_bounds__(256) void k4_fused(
    const float* __restrict__ protok,
    const float* __restrict__ hb, const float* __restrict__ pi,
    const float* __restrict__ w_att, const float* __restrict__ w_aug,
    const u16* __restrict__ QPb, const u16* __restrict__ KHb,
    const u16* __restrict__ VTb, u16* __restrict__ Ob,
    float* __restrict__ wsf) {
  const int k0 = blockIdx.x*64;
  const int bh = blockIdx.y, b = bh>>3, h = bh&7;
  const float* tab = ((h < 4) ? hb : pi) + (size_t)b*LL*LL;
  const int t = threadIdx.x;
  const int w = t>>6, lane = t&63, i = lane&15, g2 = lane>>4;
  const int qlb = 16*w + g2*4;

  __shared__ u16 Pt[64][72];
  __shared__ float Msk[1024];
  __shared__ float rg[4], rt[4], rn[4];

  // inline fold: gmax (1024), tmax/tmin (256 each)
  {
    float gm = -INFINITY;
    #pragma unroll
    for (int j=0;j<4;++j) gm = fmaxf(gm, wsf[P_GMAX + j*256 + t]);
    float tm = wsf[P_TMAX + t], tn = wsf[P_TMIN + t];
    #pragma unroll
    for (int o = 32; o > 0; o >>= 1) {
      gm = fmaxf(gm, __shfl_down(gm, o));
      tm = fmaxf(tm, __shfl_down(tm, o));
      tn = fminf(tn, __shfl_down(tn, o));
    }
    if (lane == 0) { rg[w] = gm; rt[w] = tm; rn[w] = tn; }
  }
  // stage mask values for this batch
  #pragma unroll
  for (int j=0;j<4;++j) {
    int l = j*256 + t;
    Msk[l] = (protok[b*LL + l] == 0.0f) ? NEGV : 0.0f;
  }
  __syncthreads();
  const float gmax  = fmaxf(fmaxf(rg[0],rg[1]), fmaxf(rg[2],rg[3]));
  const float tmaxr = fmaxf(fmaxf(rt[0],rt[1]), fmaxf(rt[2],rt[3]));
  const float tminr = fminf(fminf(rn[0],rn[1]), fminf(rn[2],rn[3]));
  const float wa = w_att[0], wg = w_aug[0];
  const float inv_g = wa / gmax;
  const float tden = (wg >= 0.0f) ? (wg * tmaxr) : (wg * tminr);
  const float inv_t = wg / tden;

  // K fragments direct (held all loop)
  const u16* Kr = KHb + ((size_t)bh*LL + k0)*DEP;
  bf16x8 kb0[4], kb1[4];
  #pragma unroll
  for (int ct=0;ct<4;++ct) {
    kb0[ct] = *(const bf16x8*)&Kr[(size_t)(ct*16+i)*DEP + g2*8];
    kb1[ct] = *(const bf16x8*)&Kr[(size_t)(ct*16+i)*DEP + 32 + g2*8];
  }
  const u16* Qbase = QPb + (size_t)bh*LL*DEP;
  const u16* Vbase = VTb + (size_t)bh*DEP*LL;
  // prologue: Q frags + tab for q0=0
  bf16x8 aq0 = *(const bf16x8*)&Qbase[(size_t)(16*w+i)*DEP + g2*8];
  bf16x8 aq1 = *(const bf16x8*)&Qbase[(size_t)(16*w+i)*DEP + 32 + g2*8];
  float tvr[4][4];
  #pragma unroll
  for (int r=0;r<4;++r)
    #pragma unroll
    for (int ct=0;ct<4;++ct)
      tvr[r][ct] = tab[(size_t)(qlb + r)*LL + k0 + ct*16 + i];

  f32x4 accO[4];
  #pragma unroll
  for (int dt=0;dt<4;++dt) accO[dt] = (f32x4){0.f,0.f,0.f,0.f};
  float lsum = 0.0f, lmax = -INFINITY;

  for (int q0 = 0; q0 < LL; q0 += 64) {
    const bool more = (q0 + 64) < LL;
    // S = Q K^T
    f32x4 s4[4];
    #pragma unroll
    for (int ct=0; ct<4; ++ct) {
      f32x4 z = (f32x4){0.f,0.f,0.f,0.f};
      z = __builtin_amdgcn_mfma_f32_16x16x32_bf16(aq0, kb0[ct], z, 0,0,0);
      z = __builtin_amdgcn_mfma_f32_16x16x32_bf16(aq1, kb1[ct], z, 0,0,0);
      s4[ct] = z;
    }
    // V fragments for this iter (needed after the Pt barrier; issue early)
    bf16x8 vv0[4], vv1[4];
    #pragma unroll
    for (int dt=0;dt<4;++dt) {
      vv0[dt] = *(const bf16x8*)&Vbase[(size_t)(dt*16+i)*LL + q0 + g2*8];
      vv1[dt] = *(const bf16x8*)&Vbase[(size_t)(dt*16+i)*LL + q0 + 32 + g2*8];
    }
    // next-iter Q frags + tab prefetch
    bf16x8 aq0n, aq1n;
    float tv2[4][4];
    if (more) {
      aq0n = *(const bf16x8*)&Qbase[(size_t)(q0+64+16*w+i)*DEP + g2*8];
      aq1n = *(const bf16x8*)&Qbase[(size_t)(q0+64+16*w+i)*DEP + 32 + g2*8];
      #pragma unroll
      for (int r=0;r<4;++r)
        #pragma unroll
        for (int ct=0;ct<4;++ct)
          tv2[r][ct] = tab[(size_t)(q0 + 64 + qlb + r)*LL + k0 + ct*16 + i];
    }
    // normalize + table + mask -> p = exp(s')
    float madd[4];
    #pragma unroll
    for (int r=0;r<4;++r) madd[r] = Msk[q0 + qlb + r];
    u32 pk_[4][2];
    #pragma unroll
    for (int ct=0;ct<4;++ct) {
      float pr[4];
      #pragma unroll
      for (int r=0;r<4;++r) {
        float sp = fmaf(s4[ct][r], inv_g, fmaf(tvr[r][ct], inv_t, madd[r]));
        lmax = fmaxf(lmax, sp);
        float p = __expf(sp);
        lsum += p;
        pr[r] = p;
      }
      pk_[ct][0] = (u32)f2b(pr[0]) | ((u32)f2b(pr[1])<<16);
      pk_[ct][1] = (u32)f2b(pr[2]) | ((u32)f2b(pr[3])<<16);
    }
    __syncthreads();   // all prior-iter Pt reads retired
    #pragma unroll
    for (int ct=0;ct<4;++ct)
      *(uint2*)&Pt[ct*16 + i][qlb] = make_uint2(pk_[ct][0], pk_[ct][1]);
    __syncthreads();   // Pt ready
    // O[k,d] += P^T V
    bf16x8 pa0 = *(const bf16x8*)&Pt[16*w + i][g2*8];
    bf16x8 pa1 = *(const bf16x8*)&Pt[16*w + i][32 + g2*8];
    #pragma unroll
    for (int dt=0; dt<4; ++dt) {
      accO[dt] = __builtin_amdgcn_mfma_f32_16x16x32_bf16(pa0, vv0[dt], accO[dt], 0,0,0);
      accO[dt] = __builtin_amdgcn_mfma_f32_16x16x32_bf16(pa1, vv1[dt], accO[dt], 0,0,0);
    }
    if (more) {
      aq0 = aq0n; aq1 = aq1n;
      #pragma unroll
      for (int r=0;r<4;++r)
        #pragma unroll
        for (int ct=0;ct<4;++ct) tvr[r][ct] = tv2[r][ct];
    }
  }
  // store O (bf16)
  #pragma unroll
  for (int dt=0;dt<4;++dt)
    #pragma unroll
    for (int r=0;r<4;++r)
      Ob[((size_t)bh*LL + k0 + qlb + r)*DEP + dt*16 + i] = f2b(accO[dt][r]);
  // block-reduce sum & max -> atomics (32 addresses, 16 contenders each)
  __shared__ float rs[4], rm[4];
  #pragma unroll
  for (int o = 32; o > 0; o >>= 1) {
    lsum += __shfl_down(lsum, o);
    lmax = fmaxf(lmax, __shfl_down(lmax, o));
  }
  if (lane == 0) { rs[w] = lsum; rm[w] = lmax; }
  __syncthreads();
  if (t == 0) {
    atomicAdd(&wsf[S_SUM + bh], rs[0]+rs[1]+rs[2]+rs[3]);
    atomicMaxF(&wsf[S_M + bh], fmaxf(fmaxf(rm[0], rm[1]), fmaxf(rm[2], rm[3])));
  }
}

// ---- K5: output projection via MFMA; inline cbh ----
__global__ __launch_bounds__(256) void k5_out(
    const float* __restrict__ protok,
    const float* __restrict__ bo,
    const u16* __restrict__ WTb, const u16* __restrict__ Ob,
    const float* __restrict__ wsf, float* __restrict__ out) {
  const int m0 = blockIdx.x*64, n0 = blockIdx.y*64;
  const int b = m0 >> 10, l0 = m0 & 1023;
  __shared__ u16 As[64][72];
  __shared__ u16 Bs[64][72];
  __shared__ float csh[8];
  const int t = threadIdx.x;
  const int w = t>>6, lane = t&63, i = lane&15, g2 = lane>>4;
  const int sr = t>>2, sc = (t&3)*16;

  // inline cbh
  __shared__ float ash[32];
  if (t < 32)
    ash[t] = wsf[S_MUL + (t>>3)] * __expf(wsf[S_M + t]) / wsf[S_SUM + t];
  __syncthreads();
  if (t < 8) {
    float amax = -INFINITY;
    #pragma unroll
    for (int j = 0; j < 32; ++j) amax = fmaxf(amax, ash[j]);
    csh[t] = (wsf[S_MUL + b] / wsf[S_SUM + b*HH + t]) / amax;
  }

  f32x4 acc[4];
  #pragma unroll
  for (int ct=0;ct<4;++ct) acc[ct] = (f32x4){0.f,0.f,0.f,0.f};

  for (int kk0 = 0; kk0 < DD; kk0 += 64) {
    const int h = kk0 >> 6;
    __syncthreads();
    {
      union { int4 v[2]; u16 u[16]; } uu;
      size_t so = ((size_t)(b*HH + h)*LL + l0 + sr)*DEP + sc;
      uu.v[0] = *(const int4*)&Ob[so];
      uu.v[1] = *(const int4*)&Ob[so+8];
      const float cs = csh[h];
      u32 pk_[8];
      #pragma unroll
      for (int j=0;j<8;++j)
        pk_[j] = (u32)f2b(b2f(uu.u[2*j])*cs) | ((u32)f2b(b2f(uu.u[2*j+1])*cs)<<16);
      *(int4*)&As[sr][sc]   = make_int4(pk_[0],pk_[1],pk_[2],pk_[3]);
      *(int4*)&As[sr][sc+8] = make_int4(pk_[4],pk_[5],pk_[6],pk_[7]);
    }
    {
      size_t src = ((size_t)(3*DD + n0 + sr))*DD + kk0 + sc;
      *(int4*)&Bs[sr][sc]   = *(const int4*)&WTb[src];
      *(int4*)&Bs[sr][sc+8] = *(const int4*)&WTb[src+8];
    }
    __syncthreads();
    bf16x8 a0 = *(const bf16x8*)&As[16*w + i][g2*8];
    bf16x8 a1 = *(const bf16x8*)&As[16*w + i][32 + g2*8];
    #pragma unroll
    for (int ct=0; ct<4; ++ct) {
      bf16x8 b0 = *(const bf16x8*)&Bs[ct*16 + i][g2*8];
      bf16x8 b1 = *(const bf16x8*)&Bs[ct*16 + i][32 + g2*8];
      acc[ct] = __builtin_amdgcn_mfma_f32_16x16x32_bf16(a0, b0, acc[ct], 0,0,0);
      acc[ct] = __builtin_amdgcn_mfma_f32_16x16x32_bf16(a1, b1, acc[ct], 0,0,0);
    }
  }
  #pragma unroll
  for (int ct=0;ct<4;++ct)
    #pragma unroll
    for (int r=0;r<4;++r) {
      int m = m0 + 16*w + g2*4 + r;
      float keep = (protok[m] != 0.0f) ? 1.0f : 0.0f;
      out[(size_t)m*DD + n0 + ct*16 + i] = (acc[ct][r] + bo[n0 + ct*16 + i]) * keep;
    }
}

extern "C" void kernel_launch(void* const* d_in, const int* in_sizes, int n_in,
                              void* d_out, int out_size, void* d_ws, size_t ws_size,
                              hipStream_t stream) {
  const float* q      = (const float*)d_in[0];
  const float* kv     = (const float*)d_in[1];
  const float* protok = (const float*)d_in[2];
  const float* hb     = (const float*)d_in[3];
  const float* pi     = (const float*)d_in[4];
  // d_in[5] cross_mask derived from protok on the fly
  const float* wq = (const float*)d_in[6];
  const float* bq = (const float*)d_in[7];
  const float* wk = (const float*)d_in[8];
  const float* bk = (const float*)d_in[9];
  const float* wv = (const float*)d_in[10];
  const float* bv = (const float*)d_in[11];
  const float* wo = (const float*)d_in[12];
  const float* bo = (const float*)d_in[13];
  const float* w_att = (const float*)d_in[14];
  const float* w_aug = (const float*)d_in[15];
  float* wsf = (float*)d_ws;
  float* out = (float*)d_out;

  u16* base = (u16*)(wsf + SCAL_F);
  u16* QPb = base;                 // [B,H,L,DEP] bf16
  u16* KHb = QPb + PER_T;          // [B,H,L,DEP] bf16
  u16* VTb = KHb + PER_T;          // [B,H,DEP,L] bf16 (transposed)
  u16* XO  = VTb + PER_T;          // 2*PER_T: Xb (prep..k1), then Ob (k4..)
  u16* WTb = XO  + 2*PER_T;        // [4][512][512] bf16 (transposed weights)
  u16* Xb  = XO;
  u16* Ob  = XO;                   // overwrites Xb (dead after k1)

  k_prep  <<<2565, 256, 0, stream>>>(q, kv, wq, wk, wv, wo, hb, pi, protok,
                                     Xb, WTb, wsf);
  k1_proj <<<dim3(64, 8, 3), 256, 0, stream>>>(protok, bq, bk, bv, Xb, WTb,
                                               QPb, KHb, VTb);
  k3_gmax <<<dim3(16, 32, 2), 256, 0, stream>>>(QPb, KHb, wsf);
  k4_fused<<<dim3(16, 32), 256, 0, stream>>>(protok, hb, pi, w_att, w_aug,
                                             QPb, KHb, VTb, Ob, wsf);
  k5_out  <<<dim3(64, 8), 256, 0, stream>>>(protok, bo, WTb, Ob, wsf, out);
}

// Round 8
// 208.401 us; speedup vs baseline: 1.3621x; 1.3621x over previous
//
#include <hip/hip_runtime.h>
#include <math.h>

#define BB 4
#define LL 1024
#define DD 512
#define HH 8
#define DEP 64
#define NEGV (-1.0e9f)

typedef __attribute__((ext_vector_type(8))) short bf16x8;
typedef __attribute__((ext_vector_type(4))) float f32x4;
typedef unsigned short u16;
typedef unsigned int u32;

// ---- scalar slots in ws (float offsets) ----
#define S_TMAX 1
#define S_TMIN 2
#define S_MUL  4     // 4
#define S_SUM  8     // 32
#define S_M    40    // 32
#define P_TMAX 128   // 256 partials (table scan)
#define P_TMIN 384   // 256 partials
#define P_GMAX 640   // 1024 partials (k3: 8 qstripes x 32 bh x 4 kz)
#define SCAL_F 1792
#define PER_T  (BB*HH*LL*DEP)   // 2097152 bf16 elems per tensor

__device__ inline u16 f2b(float x) {
  u32 u = __float_as_uint(x);
  return (u16)((u + 0x7FFFu + ((u >> 16) & 1u)) >> 16);
}
__device__ inline float b2f(u16 h) { return __uint_as_float(((u32)h) << 16); }

__device__ inline void atomicMaxF(float* addr, float val) {
  unsigned int* ua = (unsigned int*)addr;
  unsigned int old = *ua;
  while (__uint_as_float(old) < val) {
    unsigned int assumed = old;
    old = atomicCAS(ua, assumed, __float_as_uint(val));
    if (old == assumed) break;
  }
}

// ---- k_prep: [0,2048) xb | [2048,2304) wt | [2304,2560) table scan
//              [2560,2564) protok count | 2564 init ----
__global__ __launch_bounds__(256) void k_prep(
    const float* __restrict__ q, const float* __restrict__ kv,
    const float* __restrict__ wq, const float* __restrict__ wk,
    const float* __restrict__ wv, const float* __restrict__ wo,
    const float* __restrict__ hb, const float* __restrict__ pi,
    const float* __restrict__ protok,
    u16* __restrict__ Xb, u16* __restrict__ WTb, float* __restrict__ ws) {
  const int bid = blockIdx.x;
  const int t = threadIdx.x;
  if (bid < 2048) {                    // ---- xb: f32 -> bf16 convert of q|kv
    int tg = bid*256 + t;
    int which = tg >> 18;
    size_t off8 = (size_t)(tg & 262143) * 8;
    const float* s = which ? kv : q;
    float4 f0 = *(const float4*)&s[off8];
    float4 f1 = *(const float4*)&s[off8 + 4];
    u32 p0 = (u32)f2b(f0.x) | ((u32)f2b(f0.y) << 16);
    u32 p1 = (u32)f2b(f0.z) | ((u32)f2b(f0.w) << 16);
    u32 p2 = (u32)f2b(f1.x) | ((u32)f2b(f1.y) << 16);
    u32 p3 = (u32)f2b(f1.z) | ((u32)f2b(f1.w) << 16);
    *(int4*)&Xb[(size_t)which*PER_T + off8] = make_int4(p0, p1, p2, p3);
  } else if (bid < 2304) {             // ---- weight transpose -> WT[g][n][k]
    const int wid = bid - 2048;
    const int g = wid >> 6, rem = wid & 63;
    const int k0 = (rem >> 3)*64, n0 = (rem & 7)*64;
    const float* W = (g==0)?wq:(g==1)?wk:(g==2)?wv:wo;
    __shared__ u16 Ls[64][72];
    {
      const int r = t>>2, c16 = (t&3)*16;
      float v[16];
      #pragma unroll
      for (int j=0;j<4;++j) {
        float4 f = *(const float4*)&W[(size_t)(k0+r)*DD + n0 + c16 + 4*j];
        v[4*j]=f.x; v[4*j+1]=f.y; v[4*j+2]=f.z; v[4*j+3]=f.w;
      }
      u32 pk_[8];
      #pragma unroll
      for (int j=0;j<8;++j) pk_[j] = (u32)f2b(v[2*j]) | ((u32)f2b(v[2*j+1])<<16);
      *(int4*)&Ls[r][c16]   = make_int4(pk_[0],pk_[1],pk_[2],pk_[3]);
      *(int4*)&Ls[r][c16+8] = make_int4(pk_[4],pk_[5],pk_[6],pk_[7]);
    }
    __syncthreads();
    {
      const int n = t>>2, kk = (t&3)*16;
      u16 u[16];
      #pragma unroll
      for (int j=0;j<16;++j) u[j] = Ls[kk+j][n];
      u32 q_[8];
      #pragma unroll
      for (int j=0;j<8;++j) q_[j] = (u32)u[2*j] | ((u32)u[2*j+1]<<16);
      size_t dst = ((size_t)(g*DD + n0 + n))*DD + k0 + kk;
      *(int4*)&WTb[dst]   = make_int4(q_[0],q_[1],q_[2],q_[3]);
      *(int4*)&WTb[dst+8] = make_int4(q_[4],q_[5],q_[6],q_[7]);
    }
  } else if (bid < 2560) {             // ---- table min/max partials
    const int g = (bid - 2304)*256 + t;
    float mx = -INFINITY, mn = INFINITY;
    #pragma unroll
    for (int rep = 0; rep < 4; ++rep) {
      float4 a[4], c[4];
      #pragma unroll
      for (int j = 0; j < 4; ++j) {
        size_t idx = (size_t)rep*262144 + (size_t)j*65536 + g;
        a[j] = ((const float4*)hb)[idx];
        c[j] = ((const float4*)pi)[idx];
      }
      #pragma unroll
      for (int j = 0; j < 4; ++j) {
        mx = fmaxf(mx, fmaxf(fmaxf(a[j].x, a[j].y), fmaxf(a[j].z, a[j].w)));
        mx = fmaxf(mx, fmaxf(fmaxf(c[j].x, c[j].y), fmaxf(c[j].z, c[j].w)));
        mn = fminf(mn, fminf(fminf(a[j].x, a[j].y), fminf(a[j].z, a[j].w)));
        mn = fminf(mn, fminf(fminf(c[j].x, c[j].y), fminf(c[j].z, c[j].w)));
      }
    }
    __shared__ float shx[4], shn[4];
    int lane = t & 63, w = t >> 6;
    #pragma unroll
    for (int o = 32; o > 0; o >>= 1) {
      mx = fmaxf(mx, __shfl_down(mx, o));
      mn = fminf(mn, __shfl_down(mn, o));
    }
    if (lane == 0) { shx[w] = mx; shn[w] = mn; }
    __syncthreads();
    if (t == 0) {
      ws[P_TMAX + bid - 2304] = fmaxf(fmaxf(shx[0], shx[1]), fmaxf(shx[2], shx[3]));
      ws[P_TMIN + bid - 2304] = fminf(fminf(shn[0], shn[1]), fminf(shn[2], shn[3]));
    }
  } else if (bid < 2564) {             // ---- protok count
    int b = bid - 2560;
    int cnt = 0;
    for (int l = t; l < LL; l += 256)
      cnt += (protok[b*LL + l] != 0.0f) ? 1 : 0;
    __shared__ int shc[4];
    int lane = t & 63, w = t >> 6;
    #pragma unroll
    for (int o = 32; o > 0; o >>= 1) cnt += __shfl_down(cnt, o);
    if (lane == 0) shc[w] = cnt;
    __syncthreads();
    if (t == 0) ws[S_MUL + b] = (float)(shc[0] + shc[1] + shc[2] + shc[3]);
  } else {                             // ---- init S_SUM / S_M
    if (t < 32) { ws[S_SUM + t] = 0.0f; ws[S_M + t] = -INFINITY; }
  }
}

// ---- K1: three input projections via MFMA, LDS-staged (R6); V stored transposed ----
__global__ __launch_bounds__(256) void k1_proj(
    const float* __restrict__ protok,
    const float* __restrict__ bq, const float* __restrict__ bk,
    const float* __restrict__ bv,
    const u16* __restrict__ Xb, const u16* __restrict__ WTb,
    u16* __restrict__ QPb, u16* __restrict__ KHb, u16* __restrict__ VTb) {
  const int gid = blockIdx.z;
  const u16* X = Xb + (gid == 0 ? 0 : (size_t)PER_T);
  const float* bia = (gid == 0) ? bq : (gid == 1) ? bk : bv;
  const int m0 = blockIdx.x*64;
  const int h  = blockIdx.y;
  __shared__ u16 As[64][72];
  __shared__ u16 Bs[64][72];
  const int t = threadIdx.x;
  const int w = t>>6, lane = t&63, i = lane&15, g2 = lane>>4;
  const int sr = t>>2, sc = (t&3)*16;

  f32x4 acc[4];
  #pragma unroll
  for (int ct=0;ct<4;++ct) acc[ct] = (f32x4){0.f,0.f,0.f,0.f};

  for (int kk0 = 0; kk0 < DD; kk0 += 64) {
    __syncthreads();
    {
      size_t sx = (size_t)(m0+sr)*DD + kk0 + sc;
      *(int4*)&As[sr][sc]   = *(const int4*)&X[sx];
      *(int4*)&As[sr][sc+8] = *(const int4*)&X[sx+8];
    }
    {
      size_t src = ((size_t)(gid*DD + h*64 + sr))*DD + kk0 + sc;
      *(int4*)&Bs[sr][sc]   = *(const int4*)&WTb[src];
      *(int4*)&Bs[sr][sc+8] = *(const int4*)&WTb[src+8];
    }
    __syncthreads();
    bf16x8 a0 = *(const bf16x8*)&As[16*w + i][g2*8];
    bf16x8 a1 = *(const bf16x8*)&As[16*w + i][32 + g2*8];
    #pragma unroll
    for (int ct=0; ct<4; ++ct) {
      bf16x8 b0 = *(const bf16x8*)&Bs[ct*16 + i][g2*8];
      bf16x8 b1 = *(const bf16x8*)&Bs[ct*16 + i][32 + g2*8];
      acc[ct] = __builtin_amdgcn_mfma_f32_16x16x32_bf16(a0, b0, acc[ct], 0,0,0);
      acc[ct] = __builtin_amdgcn_mfma_f32_16x16x32_bf16(a1, b1, acc[ct], 0,0,0);
    }
  }
  __syncthreads();
  const int lrow = 16*w + g2*4;
  if (gid == 2) {
    #pragma unroll
    for (int ct=0;ct<4;++ct)
      #pragma unroll
      for (int r=0;r<4;++r)
        As[lrow + r][ct*16 + i] = f2b(acc[ct][r] + bia[h*64 + ct*16 + i]);
    __syncthreads();
    const int b = m0 >> 10, l0 = m0 & 1023;
    const int d = t>>2, lc = (t&3)*16;
    u16 u[16];
    #pragma unroll
    for (int j=0;j<16;++j) u[j] = As[lc+j][d];
    u32 q_[8];
    #pragma unroll
    for (int j=0;j<8;++j) q_[j] = (u32)u[2*j] | ((u32)u[2*j+1]<<16);
    size_t dst = ((size_t)(b*HH + h)*DEP + d)*LL + l0 + lc;
    *(int4*)&VTb[dst]   = make_int4(q_[0],q_[1],q_[2],q_[3]);
    *(int4*)&VTb[dst+8] = make_int4(q_[4],q_[5],q_[6],q_[7]);
  } else {
    u16* Y = (gid == 0) ? QPb : KHb;
    #pragma unroll
    for (int ct=0;ct<4;++ct)
      #pragma unroll
      for (int r=0;r<4;++r) {
        int m = m0 + lrow + r;
        float keep = (gid == 0) ? ((protok[m] != 0.0f) ? 1.0f : 0.0f) : 1.0f;
        int b = m >> 10, l = m & 1023;
        float val = (acc[ct][r] + bia[h*64 + ct*16 + i]) * keep;
        Y[((size_t)(b*HH + h)*LL + l)*DEP + ct*16 + i] = f2b(val);
      }
  }
}

// ---- K3: partial max of raw QK^T; 128 q-rows x 4 K-tiles per block (R6) ----
__global__ __launch_bounds__(256) void k3_gmax(
    const u16* __restrict__ QPb, const u16* __restrict__ KHb,
    float* __restrict__ wsf) {
  const int q0 = blockIdx.x*128, bh = blockIdx.y, kz = blockIdx.z;
  __shared__ u16 Qs[2][64][72];
  __shared__ u16 Ks[2][64][72];
  const int t = threadIdx.x;
  const int w = t>>6, lane = t&63, i = lane&15, g2 = lane>>4;
  const int sr = t>>2, sc = (t&3)*16;
  const u16* Qb = QPb + (size_t)bh*LL*DEP;
  const u16* Kb = KHb + (size_t)bh*LL*DEP;
  #pragma unroll
  for (int qs = 0; qs < 2; ++qs) {
    size_t sq = (size_t)(q0 + qs*64 + sr)*DEP + sc;
    *(int4*)&Qs[qs][sr][sc]   = *(const int4*)&Qb[sq];
    *(int4*)&Qs[qs][sr][sc+8] = *(const int4*)&Qb[sq+8];
  }
  const int kb = kz*4;
  int4 rn0 = *(const int4*)&Kb[(size_t)(kb*64 + sr)*DEP + sc];
  int4 rn1 = *(const int4*)&Kb[(size_t)(kb*64 + sr)*DEP + sc + 8];
  __syncthreads();
  *(int4*)&Ks[0][sr][sc]   = rn0;
  *(int4*)&Ks[0][sr][sc+8] = rn1;
  rn0 = *(const int4*)&Kb[(size_t)((kb+1)*64 + sr)*DEP + sc];
  rn1 = *(const int4*)&Kb[(size_t)((kb+1)*64 + sr)*DEP + sc + 8];
  __syncthreads();
  bf16x8 a0[2], a1[2];
  #pragma unroll
  for (int qs = 0; qs < 2; ++qs) {
    a0[qs] = *(const bf16x8*)&Qs[qs][16*w + i][g2*8];
    a1[qs] = *(const bf16x8*)&Qs[qs][16*w + i][32 + g2*8];
  }
  float mx = -INFINITY;
  for (int kt = 0; kt < 4; ++kt) {
    const int cur = kt & 1;
    #pragma unroll
    for (int ct=0;ct<4;++ct) {
      bf16x8 b0 = *(const bf16x8*)&Ks[cur][ct*16 + i][g2*8];
      bf16x8 b1 = *(const bf16x8*)&Ks[cur][ct*16 + i][32 + g2*8];
      #pragma unroll
      for (int qs=0;qs<2;++qs) {
        f32x4 z = (f32x4){0.f,0.f,0.f,0.f};
        z = __builtin_amdgcn_mfma_f32_16x16x32_bf16(a0[qs], b0, z, 0,0,0);
        z = __builtin_amdgcn_mfma_f32_16x16x32_bf16(a1[qs], b1, z, 0,0,0);
        mx = fmaxf(mx, fmaxf(fmaxf(z[0],z[1]), fmaxf(z[2],z[3])));
      }
    }
    if (kt < 3) {
      __syncthreads();
      *(int4*)&Ks[cur^1][sr][sc]   = rn0;
      *(int4*)&Ks[cur^1][sr][sc+8] = rn1;
      if (kt < 2) {
        rn0 = *(const int4*)&Kb[(size_t)((kb+kt+2)*64 + sr)*DEP + sc];
        rn1 = *(const int4*)&Kb[(size_t)((kb+kt+2)*64 + sr)*DEP + sc + 8];
      }
      __syncthreads();
    }
  }
  __shared__ float red[4];
  #pragma unroll
  for (int o = 32; o > 0; o >>= 1) mx = fmaxf(mx, __shfl_down(mx, o));
  if (lane == 0) red[w] = mx;
  __syncthreads();
  if (t == 0)
    wsf[P_GMAX + (bh*8 + blockIdx.x)*4 + kz] =
        fmaxf(fmaxf(red[0],red[1]), fmaxf(red[2],red[3]));
}

// ---- K4: fused, two q-tiles per iteration, z=1 ----
__global__ __launch_bounds__(256) void k4_fused(
    const float* __restrict__ protok,
    const float* __restrict__ hb, const float* __restrict__ pi,
    const float* __restrict__ w_att, const float* __restrict__ w_aug,
    const u16* __restrict__ QPb, const u16* __restrict__ KHb,
    const u16* __restrict__ VTb, u16* __restrict__ Ob,
    float* __restrict__ wsf) {
  const int k0 = blockIdx.x*64;
  const int bh = blockIdx.y, b = bh>>3, h = bh&7;
  const float* tab = ((h < 4) ? hb : pi) + (size_t)b*LL*LL;
  const int t = threadIdx.x;
  const int w = t>>6, lane = t&63, i = lane&15, g2 = lane>>4;
  const int sr = t>>2, sc = (t&3)*16;
  const int qlb = 16*w + g2*4;

  __shared__ u16 Ks[64][72];
  __shared__ u16 Vt[2][64][72];
  __shared__ u16 Pt[2][64][72];
  __shared__ float Msk[1024];
  __shared__ float rg[4], rt[4], rn[4];

  // inline folds: gmax (1024 partials), tmax/tmin (256 each)
  {
    float gm = -INFINITY;
    #pragma unroll
    for (int j=0;j<4;++j) gm = fmaxf(gm, wsf[P_GMAX + j*256 + t]);
    float tm = wsf[P_TMAX + t], tn = wsf[P_TMIN + t];
    #pragma unroll
    for (int o = 32; o > 0; o >>= 1) {
      gm = fmaxf(gm, __shfl_down(gm, o));
      tm = fmaxf(tm, __shfl_down(tm, o));
      tn = fminf(tn, __shfl_down(tn, o));
    }
    if (lane == 0) { rg[w] = gm; rt[w] = tm; rn[w] = tn; }
  }
  #pragma unroll
  for (int j=0;j<4;++j) {
    int l = j*256 + t;
    Msk[l] = (protok[b*LL + l] == 0.0f) ? NEGV : 0.0f;
  }
  { // stage K (coalesced, once)
    size_t sk = ((size_t)bh*LL + k0 + sr)*DEP + sc;
    *(int4*)&Ks[sr][sc]   = *(const int4*)&KHb[sk];
    *(int4*)&Ks[sr][sc+8] = *(const int4*)&KHb[sk+8];
  }
  const u16* Qbase = QPb + (size_t)bh*LL*DEP;
  const u16* Vbase = VTb + (size_t)bh*DEP*LL;
  // prologue prefetch: Q frags (direct, per-wave rows), V int4, tab for tiles 0/64
  bf16x8 aqA0 = *(const bf16x8*)&Qbase[(size_t)(16*w+i)*DEP + g2*8];
  bf16x8 aqA1 = *(const bf16x8*)&Qbase[(size_t)(16*w+i)*DEP + 32 + g2*8];
  bf16x8 aqB0 = *(const bf16x8*)&Qbase[(size_t)(64+16*w+i)*DEP + g2*8];
  bf16x8 aqB1 = *(const bf16x8*)&Qbase[(size_t)(64+16*w+i)*DEP + 32 + g2*8];
  int4 rvA0 = *(const int4*)&Vbase[(size_t)sr*LL + sc];
  int4 rvA1 = *(const int4*)&Vbase[(size_t)sr*LL + sc + 8];
  int4 rvB0 = *(const int4*)&Vbase[(size_t)sr*LL + 64 + sc];
  int4 rvB1 = *(const int4*)&Vbase[(size_t)sr*LL + 64 + sc + 8];
  float tvA[4][4], tvB[4][4];
  #pragma unroll
  for (int r=0;r<4;++r)
    #pragma unroll
    for (int ct=0;ct<4;++ct) {
      tvA[r][ct] = tab[(size_t)(qlb + r)*LL + k0 + ct*16 + i];
      tvB[r][ct] = tab[(size_t)(64 + qlb + r)*LL + k0 + ct*16 + i];
    }
  __syncthreads();
  const float gmax  = fmaxf(fmaxf(rg[0],rg[1]), fmaxf(rg[2],rg[3]));
  const float tmaxr = fmaxf(fmaxf(rt[0],rt[1]), fmaxf(rt[2],rt[3]));
  const float tminr = fminf(fminf(rn[0],rn[1]), fminf(rn[2],rn[3]));
  const float wa = w_att[0], wg = w_aug[0];
  const float inv_g = wa / gmax;
  const float tden  = (wg >= 0.0f) ? (wg * tmaxr) : (wg * tminr);
  const float inv_t = wg / tden;
  bf16x8 kb0[4], kb1[4];
  #pragma unroll
  for (int ct=0;ct<4;++ct) {
    kb0[ct] = *(const bf16x8*)&Ks[ct*16 + i][g2*8];
    kb1[ct] = *(const bf16x8*)&Ks[ct*16 + i][32 + g2*8];
  }
  f32x4 accO[4];
  #pragma unroll
  for (int dt=0;dt<4;++dt) accO[dt] = (f32x4){0.f,0.f,0.f,0.f};
  float lsum = 0.0f, lmax = -INFINITY;

  for (int q0 = 0; q0 < LL; q0 += 128) {
    const bool more = (q0 + 128) < LL;
    __syncthreads();                 // prior iter's Vt/Pt reads retired
    *(int4*)&Vt[0][sr][sc]   = rvA0;
    *(int4*)&Vt[0][sr][sc+8] = rvA1;
    *(int4*)&Vt[1][sr][sc]   = rvB0;
    *(int4*)&Vt[1][sr][sc+8] = rvB1;
    __syncthreads();                 // Vt visible
    // prefetch next iteration's V + Q frags (full-iteration latency cover)
    bf16x8 aqA0n, aqA1n, aqB0n, aqB1n;
    if (more) {
      rvA0 = *(const int4*)&Vbase[(size_t)sr*LL + q0 + 128 + sc];
      rvA1 = *(const int4*)&Vbase[(size_t)sr*LL + q0 + 128 + sc + 8];
      rvB0 = *(const int4*)&Vbase[(size_t)sr*LL + q0 + 192 + sc];
      rvB1 = *(const int4*)&Vbase[(size_t)sr*LL + q0 + 192 + sc + 8];
      aqA0n = *(const bf16x8*)&Qbase[(size_t)(q0+128+16*w+i)*DEP + g2*8];
      aqA1n = *(const bf16x8*)&Qbase[(size_t)(q0+128+16*w+i)*DEP + 32 + g2*8];
      aqB0n = *(const bf16x8*)&Qbase[(size_t)(q0+192+16*w+i)*DEP + g2*8];
      aqB1n = *(const bf16x8*)&Qbase[(size_t)(q0+192+16*w+i)*DEP + 32 + g2*8];
    }
    // S = Q K^T for both tiles (16 MFMA)
    f32x4 sA[4], sB[4];
    #pragma unroll
    for (int ct=0; ct<4; ++ct) {
      f32x4 zA = (f32x4){0.f,0.f,0.f,0.f};
      zA = __builtin_amdgcn_mfma_f32_16x16x32_bf16(aqA0, kb0[ct], zA, 0,0,0);
      zA = __builtin_amdgcn_mfma_f32_16x16x32_bf16(aqA1, kb1[ct], zA, 0,0,0);
      sA[ct] = zA;
      f32x4 zB = (f32x4){0.f,0.f,0.f,0.f};
      zB = __builtin_amdgcn_mfma_f32_16x16x32_bf16(aqB0, kb0[ct], zB, 0,0,0);
      zB = __builtin_amdgcn_mfma_f32_16x16x32_bf16(aqB1, kb1[ct], zB, 0,0,0);
      sB[ct] = zB;
    }
    // next-iter tab prefetch
    float t2A[4][4], t2B[4][4];
    if (more) {
      #pragma unroll
      for (int r=0;r<4;++r)
        #pragma unroll
        for (int ct=0;ct<4;++ct) {
          t2A[r][ct] = tab[(size_t)(q0 + 128 + qlb + r)*LL + k0 + ct*16 + i];
          t2B[r][ct] = tab[(size_t)(q0 + 192 + qlb + r)*LL + k0 + ct*16 + i];
        }
    }
    // exp phase, both tiles
    float mA[4], mB[4];
    #pragma unroll
    for (int r=0;r<4;++r) {
      mA[r] = Msk[q0 + qlb + r];
      mB[r] = Msk[q0 + 64 + qlb + r];
    }
    #pragma unroll
    for (int ct=0;ct<4;++ct) {
      float pA[4], pB[4];
      #pragma unroll
      for (int r=0;r<4;++r) {
        float spA = fmaf(sA[ct][r], inv_g, fmaf(tvA[r][ct], inv_t, mA[r]));
        float spB = fmaf(sB[ct][r], inv_g, fmaf(tvB[r][ct], inv_t, mB[r]));
        lmax = fmaxf(lmax, fmaxf(spA, spB));
        pA[r] = __expf(spA);
        pB[r] = __expf(spB);
        lsum += pA[r] + pB[r];
      }
      *(uint2*)&Pt[0][ct*16 + i][qlb] =
          make_uint2((u32)f2b(pA[0]) | ((u32)f2b(pA[1])<<16),
                     (u32)f2b(pA[2]) | ((u32)f2b(pA[3])<<16));
      *(uint2*)&Pt[1][ct*16 + i][qlb] =
          make_uint2((u32)f2b(pB[0]) | ((u32)f2b(pB[1])<<16),
                     (u32)f2b(pB[2]) | ((u32)f2b(pB[3])<<16));
    }
    __syncthreads();                 // Pt visible
    // PV both tiles (16 MFMA)
    bf16x8 paA0 = *(const bf16x8*)&Pt[0][16*w + i][g2*8];
    bf16x8 paA1 = *(const bf16x8*)&Pt[0][16*w + i][32 + g2*8];
    bf16x8 paB0 = *(const bf16x8*)&Pt[1][16*w + i][g2*8];
    bf16x8 paB1 = *(const bf16x8*)&Pt[1][16*w + i][32 + g2*8];
    #pragma unroll
    for (int dt=0; dt<4; ++dt) {
      bf16x8 vA0 = *(const bf16x8*)&Vt[0][dt*16 + i][g2*8];
      bf16x8 vA1 = *(const bf16x8*)&Vt[0][dt*16 + i][32 + g2*8];
      accO[dt] = __builtin_amdgcn_mfma_f32_16x16x32_bf16(paA0, vA0, accO[dt], 0,0,0);
      accO[dt] = __builtin_amdgcn_mfma_f32_16x16x32_bf16(paA1, vA1, accO[dt], 0,0,0);
      bf16x8 vB0 = *(const bf16x8*)&Vt[1][dt*16 + i][g2*8];
      bf16x8 vB1 = *(const bf16x8*)&Vt[1][dt*16 + i][32 + g2*8];
      accO[dt] = __builtin_amdgcn_mfma_f32_16x16x32_bf16(paB0, vB0, accO[dt], 0,0,0);
      accO[dt] = __builtin_amdgcn_mfma_f32_16x16x32_bf16(paB1, vB1, accO[dt], 0,0,0);
    }
    if (more) {
      aqA0 = aqA0n; aqA1 = aqA1n; aqB0 = aqB0n; aqB1 = aqB1n;
      #pragma unroll
      for (int r=0;r<4;++r)
        #pragma unroll
        for (int ct=0;ct<4;++ct) { tvA[r][ct] = t2A[r][ct]; tvB[r][ct] = t2B[r][ct]; }
    }
  }
  // store O (bf16)
  #pragma unroll
  for (int dt=0;dt<4;++dt)
    #pragma unroll
    for (int r=0;r<4;++r)
      Ob[((size_t)bh*LL + k0 + qlb + r)*DEP + dt*16 + i] = f2b(accO[dt][r]);
  // block-reduce sum & max -> atomics (32 addresses, 16 contenders each)
  __shared__ float rs[4], rm[4];
  #pragma unroll
  for (int o = 32; o > 0; o >>= 1) {
    lsum += __shfl_down(lsum, o);
    lmax = fmaxf(lmax, __shfl_down(lmax, o));
  }
  if (lane == 0) { rs[w] = lsum; rm[w] = lmax; }
  __syncthreads();
  if (t == 0) {
    atomicAdd(&wsf[S_SUM + bh], rs[0]+rs[1]+rs[2]+rs[3]);
    atomicMaxF(&wsf[S_M + bh], fmaxf(fmaxf(rm[0], rm[1]), fmaxf(rm[2], rm[3])));
  }
}

// ---- K5: output projection via MFMA; inline cbh ----
__global__ __launch_bounds__(256) void k5_out(
    const float* __restrict__ protok,
    const float* __restrict__ bo,
    const u16* __restrict__ WTb, const u16* __restrict__ Ob,
    const float* __restrict__ wsf, float* __restrict__ out) {
  const int m0 = blockIdx.x*64, n0 = blockIdx.y*64;
  const int b = m0 >> 10, l0 = m0 & 1023;
  __shared__ u16 As[64][72];
  __shared__ u16 Bs[64][72];
  __shared__ float csh[8];
  const int t = threadIdx.x;
  const int w = t>>6, lane = t&63, i = lane&15, g2 = lane>>4;
  const int sr = t>>2, sc = (t&3)*16;

  // inline cbh
  __shared__ float ash[32];
  if (t < 32)
    ash[t] = wsf[S_MUL + (t>>3)] * __expf(wsf[S_M + t]) / wsf[S_SUM + t];
  __syncthreads();
  if (t < 8) {
    float amax = -INFINITY;
    #pragma unroll
    for (int j = 0; j < 32; ++j) amax = fmaxf(amax, ash[j]);
    csh[t] = (wsf[S_MUL + b] / wsf[S_SUM + b*HH + t]) / amax;
  }

  f32x4 acc[4];
  #pragma unroll
  for (int ct=0;ct<4;++ct) acc[ct] = (f32x4){0.f,0.f,0.f,0.f};

  for (int kk0 = 0; kk0 < DD; kk0 += 64) {
    const int h = kk0 >> 6;
    __syncthreads();
    {
      union { int4 v[2]; u16 u[16]; } uu;
      size_t so = ((size_t)(b*HH + h)*LL + l0 + sr)*DEP + sc;
      uu.v[0] = *(const int4*)&Ob[so];
      uu.v[1] = *(const int4*)&Ob[so+8];
      const float cs = csh[h];
      u32 pk_[8];
      #pragma unroll
      for (int j=0;j<8;++j)
        pk_[j] = (u32)f2b(b2f(uu.u[2*j])*cs) | ((u32)f2b(b2f(uu.u[2*j+1])*cs)<<16);
      *(int4*)&As[sr][sc]   = make_int4(pk_[0],pk_[1],pk_[2],pk_[3]);
      *(int4*)&As[sr][sc+8] = make_int4(pk_[4],pk_[5],pk_[6],pk_[7]);
    }
    {
      size_t src = ((size_t)(3*DD + n0 + sr))*DD + kk0 + sc;
      *(int4*)&Bs[sr][sc]   = *(const int4*)&WTb[src];
      *(int4*)&Bs[sr][sc+8] = *(const int4*)&WTb[src+8];
    }
    __syncthreads();
    bf16x8 a0 = *(const bf16x8*)&As[16*w + i][g2*8];
    bf16x8 a1 = *(const bf16x8*)&As[16*w + i][32 + g2*8];
    #pragma unroll
    for (int ct=0; ct<4; ++ct) {
      bf16x8 b0 = *(const bf16x8*)&Bs[ct*16 + i][g2*8];
      bf16x8 b1 = *(const bf16x8*)&Bs[ct*16 + i][32 + g2*8];
      acc[ct] = __builtin_amdgcn_mfma_f32_16x16x32_bf16(a0, b0, acc[ct], 0,0,0);
      acc[ct] = __builtin_amdgcn_mfma_f32_16x16x32_bf16(a1, b1, acc[ct], 0,0,0);
    }
  }
  #pragma unroll
  for (int ct=0;ct<4;++ct)
    #pragma unroll
    for (int r=0;r<4;++r) {
      int m = m0 + 16*w + g2*4 + r;
      float keep = (protok[m] != 0.0f) ? 1.0f : 0.0f;
      out[(size_t)m*DD + n0 + ct*16 + i] = (acc[ct][r] + bo[n0 + ct*16 + i]) * keep;
    }
}

extern "C" void kernel_launch(void* const* d_in, const int* in_sizes, int n_in,
                              void* d_out, int out_size, void* d_ws, size_t ws_size,
                              hipStream_t stream) {
  const float* q      = (const float*)d_in[0];
  const float* kv     = (const float*)d_in[1];
  const float* protok = (const float*)d_in[2];
  const float* hb     = (const float*)d_in[3];
  const float* pi     = (const float*)d_in[4];
  // d_in[5] cross_mask derived from protok on the fly
  const float* wq = (const float*)d_in[6];
  const float* bq = (const float*)d_in[7];
  const float* wk = (const float*)d_in[8];
  const float* bk = (const float*)d_in[9];
  const float* wv = (const float*)d_in[10];
  const float* bv = (const float*)d_in[11];
  const float* wo = (const float*)d_in[12];
  const float* bo = (const float*)d_in[13];
  const float* w_att = (const float*)d_in[14];
  const float* w_aug = (const float*)d_in[15];
  float* wsf = (float*)d_ws;
  float* out = (float*)d_out;

  u16* base = (u16*)(wsf + SCAL_F);
  u16* QPb = base;                 // [B,H,L,DEP] bf16
  u16* KHb = QPb + PER_T;          // [B,H,L,DEP] bf16
  u16* VTb = KHb + PER_T;          // [B,H,DEP,L] bf16 (transposed)
  u16* XO  = VTb + PER_T;          // 2*PER_T: Xb (prep..k1), then Ob (k4..)
  u16* WTb = XO  + 2*PER_T;        // [4][512][512] bf16 (transposed weights)
  u16* Xb  = XO;
  u16* Ob  = XO;                   // overwrites Xb (dead after k1)

  k_prep  <<<2565, 256, 0, stream>>>(q, kv, wq, wk, wv, wo, hb, pi, protok,
                                     Xb, WTb, wsf);
  k1_proj <<<dim3(64, 8, 3), 256, 0, stream>>>(protok, bq, bk, bv, Xb, WTb,
                                               QPb, KHb, VTb);
  k3_gmax <<<dim3(8, 32, 4), 256, 0, stream>>>(QPb, KHb, wsf);
  k4_fused<<<dim3(16, 32), 256, 0, stream>>>(protok, hb, pi, w_att, w_aug,
                                             QPb, KHb, VTb, Ob, wsf);
  k5_out  <<<dim3(64, 8), 256, 0, stream>>>(protok, bo, WTb, Ob, wsf, out);
}